// Round 5
// baseline (200.974 us; speedup 1.0000x reference)
//
#include <hip/hip_runtime.h>

#define N_ROWS 8192
#define DIM    512

typedef __attribute__((ext_vector_type(8))) short frag_ab;  // 8 bf16 (4 VGPRs)
typedef __attribute__((ext_vector_type(4))) float frag_cd;  // 4 fp32 acc

__device__ __forceinline__ unsigned short f2bf(float f) {
    unsigned u = __float_as_uint(f);
    u += 0x7FFFu + ((u >> 16) & 1u);   // RNE
    return (unsigned short)(u >> 16);
}
__device__ __forceinline__ unsigned pack2(float a, float b) {
    return (unsigned)f2bf(a) | ((unsigned)f2bf(b) << 16);
}
// order-preserving f32 -> u32 key (monotone), so atomicMax(uint) == float max
__device__ __forceinline__ unsigned enc_f32(float f) {
    unsigned u = __float_as_uint(f);
    return (u & 0x80000000u) ? ~u : (u | 0x80000000u);
}
__device__ __forceinline__ float dec_f32(unsigned k) {
    return __uint_as_float((k & 0x80000000u) ? (k & 0x7FFFFFFFu) : ~k);
}

// ---- TILED bf16 layout ----
// 16B-unit index = cr*1024 + cc*64 + cg*16 + rin
//   cr = row>>4, rin = row&15, cc = col>>5, cg = (col>>3)&3  (8 elems per unit)
// KEY PROPERTY: unit (cg*16+rin) == the 16x16x32 MFMA A/B fragment layout
// (lane l15 needs row=l15, K-group q -> unit q*16+l15 = lane). So a wave loads
// its fragment with ONE coalesced global_load_dwordx4 (lane L reads unit L,
// 1KB contiguous) -- no LDS, no barriers needed at all.

// ---- kernel 1: fused convert-to-tiled + fp32 diag + max-key init ----
__global__ __launch_bounds__(256) void k_prep(const float* __restrict__ imgs,
                                              const float* __restrict__ caps,
                                              uint4* __restrict__ bimgs,
                                              uint4* __restrict__ bcaps,
                                              float* __restrict__ diag,
                                              unsigned* __restrict__ rowmax,
                                              unsigned* __restrict__ colmax) {
    const int cr = blockIdx.x;            // 0..511
    const int t  = threadIdx.x;           // 0..255
    const int rin = t & 15;
    const int cg  = (t >> 4) & 3;
    const int row = cr * 16 + rin;
    float dsum = 0.f;
    #pragma unroll
    for (int i = 0; i < 4; ++i) {
        const int cc = i * 4 + (t >> 6);
        const int colbase = cc * 32 + cg * 8;
        const float4* ip = (const float4*)(imgs + (size_t)row * DIM + colbase);
        const float4* cp = (const float4*)(caps + (size_t)row * DIM + colbase);
        float4 a0 = ip[0], a1 = ip[1];
        float4 b0 = cp[0], b1 = cp[1];
        uint4 oa, ob;
        oa.x = pack2(a0.x, a0.y); oa.y = pack2(a0.z, a0.w);
        oa.z = pack2(a1.x, a1.y); oa.w = pack2(a1.z, a1.w);
        ob.x = pack2(b0.x, b0.y); ob.y = pack2(b0.z, b0.w);
        ob.z = pack2(b1.x, b1.y); ob.w = pack2(b1.z, b1.w);
        const int u = i * 256 + t;        // == cc*64 + cg*16 + rin  (contiguous store)
        bimgs[(size_t)cr * 1024 + u] = oa;
        bcaps[(size_t)cr * 1024 + u] = ob;
        dsum += a0.x * b0.x + a0.y * b0.y + a0.z * b0.z + a0.w * b0.w
              + a1.x * b1.x + a1.y * b1.y + a1.z * b1.z + a1.w * b1.w;
    }
    __shared__ float sred[256];
    sred[t] = dsum;
    __syncthreads();
    if (t < 16) {
        float s = 0.f;
        #pragma unroll
        for (int k = 0; k < 16; ++k) s += sred[t + 16 * k];
        const int r = cr * 16 + t;
        diag[r] = s; rowmax[r] = 0u; colmax[r] = 0u;
    }
}

// ---- kernel 2: fused bf16 NT-GEMM + diag flip + row/col max ----
// NO LDS, NO BARRIERS: each wave computes 64x64, loading A/B fragments
// directly from the tiled layout (perfectly coalesced, 1KB/instr). K-loop is
// load<->MFMA interleaved; compiler inserts per-operand vmcnt (never a full
// drain). Reuse: 2 waves share each A-panel chunk and 2 share each B chunk
// (L1); x%8-fixed XCD mapping keeps each XCD's 8 B-panels (1MB) L2-resident.
__global__ __launch_bounds__(256) void k_gemm(const uint4* __restrict__ A,
                                              const uint4* __restrict__ B,
                                              unsigned* __restrict__ rowmax,
                                              unsigned* __restrict__ colmax) {
    const int tid = threadIdx.x;
    const int w = tid >> 6, lane = tid & 63;
    const int i0 = (int)blockIdx.y << 7, j0 = (int)blockIdx.x << 7;
    const int q = lane >> 4, l15 = lane & 15;
    const int wrow = (w >> 1) << 6, wcol = (w & 1) << 6;

    // chunk-row base (uint4 units): chunk (cr,cc) starts at (cr*16+cc)*64
    const uint4* Abase = A + (size_t)(((i0 + wrow) >> 4) << 10) + lane;
    const uint4* Bbase = B + (size_t)(((j0 + wcol) >> 4) << 10) + lane;

    frag_cd acc[4][4] = {};

    #pragma unroll 2
    for (int kc = 0; kc < 16; ++kc) {       // K-chunk = 32 elems
        frag_ab af[4], bfr[4];
        #pragma unroll
        for (int r = 0; r < 4; ++r)
            af[r] = *(const frag_ab*)(Abase + (r << 10) + (kc << 6));
        #pragma unroll
        for (int c = 0; c < 4; ++c)
            bfr[c] = *(const frag_ab*)(Bbase + (c << 10) + (kc << 6));
        #pragma unroll
        for (int r = 0; r < 4; ++r)
            #pragma unroll
            for (int c = 0; c < 4; ++c)
                acc[r][c] = __builtin_amdgcn_mfma_f32_16x16x32_bf16(af[r], bfr[c], acc[r][c], 0, 0, 0);
    }

    // ---- epilogue: diagonal flip + row/col max + device atomics ----
    // C/D layout: col = lane&15, row = (lane>>4)*4 + reg  [m89-verified]
    const bool dblk = (i0 == j0);
    #pragma unroll
    for (int r = 0; r < 4; ++r)
        #pragma unroll
        for (int c = 0; c < 4; ++c)
            #pragma unroll
            for (int g = 0; g < 4; ++g) {
                float f = acc[r][c][g];
                if (dblk && (wrow + (r << 4) + (q << 2) + g) == (wcol + (c << 4) + l15))
                    f = -f;   // s[i][i] = -diag
                acc[r][c][g] = f;
            }

    // row maxes: reduce over c (in-reg) then over lane&15 (xor 1,2,4,8)
    #pragma unroll
    for (int r = 0; r < 4; ++r)
        #pragma unroll
        for (int g = 0; g < 4; ++g) {
            float m = fmaxf(fmaxf(acc[r][0][g], acc[r][1][g]),
                            fmaxf(acc[r][2][g], acc[r][3][g]));
            m = fmaxf(m, __shfl_xor(m, 1, 64));
            m = fmaxf(m, __shfl_xor(m, 2, 64));
            m = fmaxf(m, __shfl_xor(m, 4, 64));
            m = fmaxf(m, __shfl_xor(m, 8, 64));
            if (l15 == 0)
                atomicMax(&rowmax[i0 + wrow + (r << 4) + (q << 2) + g], enc_f32(m));
        }
    // col maxes: reduce over r,g (in-reg) then over q (xor 16,32)
    #pragma unroll
    for (int c = 0; c < 4; ++c) {
        float m = acc[0][c][0];
        #pragma unroll
        for (int r = 0; r < 4; ++r)
            #pragma unroll
            for (int g = 0; g < 4; ++g) m = fmaxf(m, acc[r][c][g]);
        m = fmaxf(m, __shfl_xor(m, 16, 64));
        m = fmaxf(m, __shfl_xor(m, 32, 64));
        if (q == 0)
            atomicMax(&colmax[j0 + wcol + (c << 4) + l15], enc_f32(m));
    }
}

// ---- kernel 3: hinge terms + scalar reduce (1024 threads, 8 iters, all
// loads independent -> issue together, ~3us) ----
__global__ __launch_bounds__(1024) void k_final(const unsigned* __restrict__ rowmax,
                                                const unsigned* __restrict__ colmax,
                                                const float* __restrict__ diag,
                                                float* __restrict__ out) {
    const int tid = threadIdx.x;
    float s = 0.f;
    #pragma unroll
    for (int i = 0; i < 8; ++i) {
        const int idx = tid + (i << 10);
        float d = diag[idx];
        s += fmaxf(dec_f32(rowmax[idx]) + 0.2f - d, 0.f);  // neg_img
        s += fmaxf(dec_f32(colmax[idx]) + 0.2f - d, 0.f);  // neg_cap
    }
    #pragma unroll
    for (int m = 1; m < 64; m <<= 1) s += __shfl_xor(s, m, 64);
    __shared__ float red[16];
    if ((tid & 63) == 0) red[tid >> 6] = s;
    __syncthreads();
    if (tid == 0) {
        float t = 0.f;
        #pragma unroll
        for (int i = 0; i < 16; ++i) t += red[i];
        out[0] = t;
    }
}

extern "C" void kernel_launch(void* const* d_in, const int* in_sizes, int n_in,
                              void* d_out, int out_size, void* d_ws, size_t ws_size,
                              hipStream_t stream) {
    const float* imgs = (const float*)d_in[0];
    const float* caps = (const float*)d_in[1];
    float* out = (float*)d_out;

    char* ws = (char*)d_ws;
    uint4* bimgs = (uint4*)ws;                                         // 8 MB tiled
    uint4* bcaps = (uint4*)(ws + 8388608);                             // 8 MB tiled
    float*    diag   = (float*)   (ws + 16777216);                     // 32 KB
    unsigned* rowmax = (unsigned*)(ws + 16777216 + 32768);             // 32 KB
    unsigned* colmax = (unsigned*)(ws + 16777216 + 65536);             // 32 KB

    k_prep<<<N_ROWS / 16, 256, 0, stream>>>(imgs, caps, bimgs, bcaps,
                                            diag, rowmax, colmax);
    k_gemm<<<dim3(64, 64), 256, 0, stream>>>(bimgs, bcaps, rowmax, colmax);
    k_final<<<1, 1024, 0, stream>>>(rowmax, colmax, diag, out);
}